// Round 5
// baseline (167.677 us; speedup 1.0000x reference)
//
#include <hip/hip_runtime.h>

#define NPOS 589824   // 64*96*96
#define LN_EPS 1e-5f

typedef _Float16 half8 __attribute__((ext_vector_type(8)));
typedef _Float16 half2_t __attribute__((ext_vector_type(2)));
typedef __fp16 fp16x2 __attribute__((ext_vector_type(2)));
typedef float f32x4 __attribute__((ext_vector_type(4)));
typedef float f32x2 __attribute__((ext_vector_type(2)));

static __device__ __forceinline__ half2_t pk16(float a, float b) {
    return __builtin_bit_cast(half2_t, __builtin_amdgcn_cvt_pkrtz(a, b));
}

#define K1_BLOCKS 576
#define K1_CPB 2      // 2 chunks of 512 positions per block: 576*2*512 == NPOS
#define YSTR 520      // row stride (f16 elems) for the shared Y tile

// ws layout (floats): [0,1024) G ; [1024,2432) M 64x22 ; [2432,2496) beta
// [4096, 4096 + K1_BLOCKS*1024) partials  (total 2.37 MB, within proven ws)

// LN + Gram kernel. Each thread owns 2 consecutive positions: 64 independent
// f32x2 loads, stats on the fly, ch 0..42 parked in REGISTERS as packed f16x2.
// Y rows: 0..42 = y channels, 43 = ones, 44 = zeros. A rows r: r<22->r,
// 22->43, else 44.  B rows r (ch 21+r): r<=22 -> 21+r (22->43=ones!), else 44.
__global__ __launch_bounds__(256) void csa_k1(
    const float* __restrict__ x, const float* __restrict__ lng,
    const float* __restrict__ lnb, float* __restrict__ partials)
{
    __shared__ __align__(16) _Float16 Y[45][YSTR];   // 46.8 KB -> 3 blocks/CU
    const int tid = threadIdx.x;
    const int lane = tid & 63;
    const int wv = tid >> 6;

    for (int i = tid; i < YSTR; i += 256) {
        Y[43][i] = (_Float16)1.0f;
        Y[44][i] = (_Float16)0.0f;
    }

    f32x4 acc00 = {0.f,0.f,0.f,0.f}, acc01 = acc00, acc10 = acc00, acc11 = acc00;
    const int row = lane & 15;
    const int sub = (lane >> 4) & 3;
    const int kbase = wv * 128 + sub * 8;            // wave's K slice: 128 wide
    const int r16 = row + 16;
    const int ra1 = (r16 < 22) ? r16 : ((r16 == 22) ? 43 : 44);
    const int rb1 = (r16 < 22) ? (r16 + 21) : ((r16 == 22) ? 43 : 44);
    const int pos0 = blockIdx.x * (K1_CPB * 512);

    for (int ck = 0; ck < K1_CPB; ++ck) {
        const int n0 = pos0 + ck * 512 + tid * 2;
        f32x2 s = {0.f, 0.f}, sq = s;
        half2_t park[43];
        #pragma unroll
        for (int c = 0; c < 64; ++c) {               // all loads independent
            f32x2 v = *(const f32x2*)(x + (size_t)c * NPOS + n0);
            s += v; sq += v * v;
            if (c < 43) park[c] = pk16(v[0], v[1]);
        }
        const f32x2 mu = s * (1.f/64.f);
        const f32x2 var = sq * (1.f/64.f) - mu * mu;
        const float rin0 = rsqrtf(fmaxf(var[0], 0.f) + LN_EPS);
        const float rin1 = rsqrtf(fmaxf(var[1], 0.f) + LN_EPS);
        #pragma unroll
        for (int c = 0; c < 43; ++c) {
            const float g = lng[c], b = lnb[c];
            const float rg0 = rin0 * g, rg1 = rin1 * g;
            const float d0 = fmaf(-mu[0], rg0, b);
            const float d1 = fmaf(-mu[1], rg1, b);
            const float y0 = fmaf((float)park[c][0], rg0, d0);
            const float y1 = fmaf((float)park[c][1], rg1, d1);
            *(half2_t*)&Y[c][tid * 2] = pk16(y0, y1);
        }
        __syncthreads();
        #pragma unroll
        for (int s2 = 0; s2 < 4; ++s2) {
            const int kk = kbase + s2 * 32;
            half8 a0 = *(const half8*)&Y[row][kk];
            half8 a1 = *(const half8*)&Y[ra1][kk];
            half8 b0 = *(const half8*)&Y[row + 21][kk];
            half8 b1 = *(const half8*)&Y[rb1][kk];
            acc00 = __builtin_amdgcn_mfma_f32_16x16x32_f16(a0, b0, acc00, 0, 0, 0);
            acc01 = __builtin_amdgcn_mfma_f32_16x16x32_f16(a0, b1, acc01, 0, 0, 0);
            acc10 = __builtin_amdgcn_mfma_f32_16x16x32_f16(a1, b0, acc10, 0, 0, 0);
            acc11 = __builtin_amdgcn_mfma_f32_16x16x32_f16(a1, b1, acc11, 0, 0, 0);
        }
        __syncthreads();
    }
    // block-level reduce of the 4 waves' fragments (reuse Y as float scratch)
    float* G32 = (float*)&Y[0][0];
    for (int e = tid; e < 1024; e += 256) G32[e] = 0.f;
    __syncthreads();
    const int r0 = (lane >> 4) * 4, c0 = lane & 15;
    #pragma unroll
    for (int r = 0; r < 4; ++r) {
        atomicAdd(&G32[(r0 + r) * 32 + c0],            acc00[r]);
        atomicAdd(&G32[(r0 + r) * 32 + 16 + c0],       acc01[r]);
        atomicAdd(&G32[(16 + r0 + r) * 32 + c0],       acc10[r]);
        atomicAdd(&G32[(16 + r0 + r) * 32 + 16 + c0],  acc11[r]);
    }
    __syncthreads();
    for (int e = tid; e < 1024; e += 256)
        partials[blockIdx.x * 1024 + e] = G32[e];
}

__global__ __launch_bounds__(256) void csa_k2(const float* __restrict__ partials,
                                              float* __restrict__ gfin)
{
    const int e = blockIdx.x * 256 + threadIdx.x;  // 0..1023
    float s = 0.f;
    for (int b = 0; b < K1_BLOCKS; ++b) s += partials[b * 1024 + e];
    gfin[e] = s;
}

__global__ void csa_k3(const float* __restrict__ G, const float* __restrict__ cw,
                       const float* __restrict__ cb, float* __restrict__ M,
                       float* __restrict__ betaO)
{
    const int c = threadIdx.x;       // 64 threads, one output row each
    __shared__ float lg[64][65];
    const float wq = cw[c], bq = cb[c];
    const int a = c / 3;
    const float Sa = G[a * 32 + 22];
    float mx = -1e30f;
    #pragma unroll
    for (int k = 0; k < 64; ++k) {
        const float wk = cw[64 + k], bk = cb[64 + k];
        const int b = (64 + k) / 3 - 21;
        const float Gab = G[a * 32 + b];
        const float Sb  = G[22 * 32 + b];
        float lo = 0.125f * (wq * wk * Gab + wq * bk * Sa + bq * wk * Sb
                             + bq * bk * (float)NPOS);
        lg[c][k] = lo;
        mx = fmaxf(mx, lo);
    }
    float sum = 0.f;
    #pragma unroll
    for (int k = 0; k < 64; ++k) {
        float e = expf(lg[c][k] - mx);
        lg[c][k] = e; sum += e;
    }
    const float inv = 1.f / sum;
    float Ml[22];
    #pragma unroll
    for (int m = 0; m < 22; ++m) Ml[m] = 0.f;
    float bacc = 0.f;
    #pragma unroll
    for (int k = 0; k < 64; ++k) {
        const float attn = lg[c][k] * inv;
        const int mm = (128 + k) / 3 - 42;
        Ml[mm] = fmaf(attn, cw[128 + k], Ml[mm]);
        bacc   = fmaf(attn, cb[128 + k], bacc);
    }
    #pragma unroll
    for (int m = 0; m < 22; ++m) M[c * 22 + m] = Ml[m];
    betaO[c] = bacc;
}

// Output kernel: 2 positions/thread, f32x2 loads, f32x2 nontemporal stores.
__global__ __launch_bounds__(256) void csa_k4(
    const float* __restrict__ x, const float* __restrict__ lng,
    const float* __restrict__ lnb, const float* __restrict__ M,
    const float* __restrict__ betaO, float* __restrict__ out)
{
    const int n0 = (blockIdx.x * 256 + threadIdx.x) * 2;
    f32x2 xv[64];
    f32x2 s = {0.f, 0.f}, sq = s;
    #pragma unroll
    for (int c = 0; c < 64; ++c) {
        f32x2 v = *(const f32x2*)(x + (size_t)c * NPOS + n0);
        xv[c] = v; s += v; sq += v * v;
    }
    const f32x2 mu = s * (1.f/64.f);
    const f32x2 var = sq * (1.f/64.f) - mu * mu;
    const float rin0 = rsqrtf(fmaxf(var[0], 0.f) + LN_EPS);
    const float rin1 = rsqrtf(fmaxf(var[1], 0.f) + LN_EPS);
    f32x2 y[22];
    #pragma unroll
    for (int m = 0; m < 22; ++m) {
        const float g = lng[42 + m], b = lnb[42 + m];
        y[m][0] = fmaf((xv[42 + m][0] - mu[0]) * rin0, g, b);
        y[m][1] = fmaf((xv[42 + m][1] - mu[1]) * rin1, g, b);
    }
    #pragma unroll
    for (int c = 0; c < 64; ++c) {
        const float bb = betaO[c];
        f32x2 a = {bb, bb};
        #pragma unroll
        for (int m = 0; m < 22; ++m) {
            const float w = M[c * 22 + m];       // uniform -> scalar
            a[0] = fmaf(w, y[m][0], a[0]);
            a[1] = fmaf(w, y[m][1], a[1]);
        }
        f32x2 o = xv[c] + a;
        __builtin_nontemporal_store(o, (f32x2*)(out + (size_t)c * NPOS + n0));
    }
}

extern "C" void kernel_launch(void* const* d_in, const int* in_sizes, int n_in,
                              void* d_out, int out_size, void* d_ws, size_t ws_size,
                              hipStream_t stream) {
    const float* x   = (const float*)d_in[0];
    const float* lng = (const float*)d_in[1];
    const float* lnb = (const float*)d_in[2];
    const float* cw  = (const float*)d_in[3];
    const float* cb  = (const float*)d_in[4];
    float* out = (float*)d_out;

    float* wsf = (float*)d_ws;
    float* Gf  = wsf;                     // 1024 floats
    float* Mf  = wsf + 1024;              // 64*22
    float* Bf  = wsf + 1024 + 64 * 22;    // 64
    float* Pf  = wsf + 4096;              // partials (576 * 1024 floats)

    hipLaunchKernelGGL(csa_k1, dim3(K1_BLOCKS), dim3(256), 0, stream,
                       x, lng, lnb, Pf);
    hipLaunchKernelGGL(csa_k2, dim3(4), dim3(256), 0, stream, Pf, Gf);
    hipLaunchKernelGGL(csa_k3, dim3(1), dim3(64), 0, stream, Gf, cw, cb, Mf, Bf);
    hipLaunchKernelGGL(csa_k4, dim3(NPOS / 512), dim3(256), 0, stream,
                       x, lng, lnb, Mf, Bf, out);
}

// Round 6
// 152.027 us; speedup vs baseline: 1.1029x; 1.1029x over previous
//
#include <hip/hip_runtime.h>

#define NPOS 589824   // 64*96*96
#define LN_EPS 1e-5f

typedef _Float16 half8 __attribute__((ext_vector_type(8)));
typedef _Float16 half2_t __attribute__((ext_vector_type(2)));
typedef float f32x4 __attribute__((ext_vector_type(4)));
typedef float f32x2 __attribute__((ext_vector_type(2)));

static __device__ __forceinline__ half2_t pk16(float a, float b) {
    return __builtin_bit_cast(half2_t, __builtin_amdgcn_cvt_pkrtz(a, b));
}

#define K1_BLOCKS 576
#define K1_CPB 2      // 2 chunks of 512 positions per block: 576*2*512 == NPOS
#define YSTR 520      // row stride (f16 elems) for the shared Y tile

// ws layout (floats): [0,1024) G ; [1024,2432) M 64x22 ; [2432,2496) beta
// [4096, 4096 + K1_BLOCKS*1024) partials  (total 2.37 MB, within proven ws)

// LN + Gram kernel. Each thread owns 2 consecutive positions: 64 independent
// f32x2 loads, stats on the fly, ch 0..42 parked in REGISTERS as packed f16x2.
// __launch_bounds__(256,3): LDS already caps at 3 blocks/CU, so give the
// scheduler ~170 VGPRs -> ~45 loads in flight (round-5 had 68 VGPRs -> MLP~2).
// Y rows: 0..42 = y channels, 43 = ones, 44 = zeros. A rows r: r<22->r,
// 22->43, else 44.  B rows r (ch 21+r): r<=22 -> 21+r (22->43=ones!), else 44.
__global__ __launch_bounds__(256, 3) void csa_k1(
    const float* __restrict__ x, const float* __restrict__ lng,
    const float* __restrict__ lnb, float* __restrict__ partials)
{
    __shared__ __align__(16) _Float16 Y[45][YSTR];   // 46.8 KB -> 3 blocks/CU
    const int tid = threadIdx.x;
    const int lane = tid & 63;
    const int wv = tid >> 6;

    for (int i = tid; i < YSTR; i += 256) {
        Y[43][i] = (_Float16)1.0f;
        Y[44][i] = (_Float16)0.0f;
    }

    f32x4 acc00 = {0.f,0.f,0.f,0.f}, acc01 = acc00, acc10 = acc00, acc11 = acc00;
    const int row = lane & 15;
    const int sub = (lane >> 4) & 3;
    const int kbase = wv * 128 + sub * 8;            // wave's K slice: 128 wide
    const int r16 = row + 16;
    const int ra1 = (r16 < 22) ? r16 : ((r16 == 22) ? 43 : 44);
    const int rb1 = (r16 < 22) ? (r16 + 21) : ((r16 == 22) ? 43 : 44);
    const int pos0 = blockIdx.x * (K1_CPB * 512);

    for (int ck = 0; ck < K1_CPB; ++ck) {
        const int n0 = pos0 + ck * 512 + tid * 2;
        f32x2 s = {0.f, 0.f}, sq = s;
        half2_t park[43];
        #pragma unroll
        for (int c = 0; c < 64; ++c) {               // all loads independent
            f32x2 v = *(const f32x2*)(x + (size_t)c * NPOS + n0);
            s += v; sq += v * v;
            if (c < 43) park[c] = pk16(v[0], v[1]);
        }
        const f32x2 mu = s * (1.f/64.f);
        const f32x2 var = sq * (1.f/64.f) - mu * mu;
        const float rin0 = rsqrtf(fmaxf(var[0], 0.f) + LN_EPS);
        const float rin1 = rsqrtf(fmaxf(var[1], 0.f) + LN_EPS);
        #pragma unroll
        for (int c = 0; c < 43; ++c) {
            const float g = lng[c], b = lnb[c];
            const float rg0 = rin0 * g, rg1 = rin1 * g;
            const float d0 = fmaf(-mu[0], rg0, b);
            const float d1 = fmaf(-mu[1], rg1, b);
            const float y0 = fmaf((float)park[c][0], rg0, d0);
            const float y1 = fmaf((float)park[c][1], rg1, d1);
            *(half2_t*)&Y[c][tid * 2] = pk16(y0, y1);
        }
        __syncthreads();
        #pragma unroll
        for (int s2 = 0; s2 < 4; ++s2) {
            const int kk = kbase + s2 * 32;
            half8 a0 = *(const half8*)&Y[row][kk];
            half8 a1 = *(const half8*)&Y[ra1][kk];
            half8 b0 = *(const half8*)&Y[row + 21][kk];
            half8 b1 = *(const half8*)&Y[rb1][kk];
            acc00 = __builtin_amdgcn_mfma_f32_16x16x32_f16(a0, b0, acc00, 0, 0, 0);
            acc01 = __builtin_amdgcn_mfma_f32_16x16x32_f16(a0, b1, acc01, 0, 0, 0);
            acc10 = __builtin_amdgcn_mfma_f32_16x16x32_f16(a1, b0, acc10, 0, 0, 0);
            acc11 = __builtin_amdgcn_mfma_f32_16x16x32_f16(a1, b1, acc11, 0, 0, 0);
        }
        __syncthreads();
    }
    // block-level reduce of the 4 waves' fragments (reuse Y as float scratch)
    float* G32 = (float*)&Y[0][0];
    for (int e = tid; e < 1024; e += 256) G32[e] = 0.f;
    __syncthreads();
    const int r0 = (lane >> 4) * 4, c0 = lane & 15;
    #pragma unroll
    for (int r = 0; r < 4; ++r) {
        atomicAdd(&G32[(r0 + r) * 32 + c0],            acc00[r]);
        atomicAdd(&G32[(r0 + r) * 32 + 16 + c0],       acc01[r]);
        atomicAdd(&G32[(16 + r0 + r) * 32 + c0],       acc10[r]);
        atomicAdd(&G32[(16 + r0 + r) * 32 + 16 + c0],  acc11[r]);
    }
    __syncthreads();
    for (int e = tid; e < 1024; e += 256)
        partials[blockIdx.x * 1024 + e] = G32[e];
}

__global__ __launch_bounds__(256) void csa_k2(const float* __restrict__ partials,
                                              float* __restrict__ gfin)
{
    const int e = blockIdx.x * 256 + threadIdx.x;  // 0..1023
    float s = 0.f;
    for (int b = 0; b < K1_BLOCKS; ++b) s += partials[b * 1024 + e];
    gfin[e] = s;
}

__global__ void csa_k3(const float* __restrict__ G, const float* __restrict__ cw,
                       const float* __restrict__ cb, float* __restrict__ M,
                       float* __restrict__ betaO)
{
    const int c = threadIdx.x;       // 64 threads, one output row each
    __shared__ float lg[64][65];
    const float wq = cw[c], bq = cb[c];
    const int a = c / 3;
    const float Sa = G[a * 32 + 22];
    float mx = -1e30f;
    #pragma unroll
    for (int k = 0; k < 64; ++k) {
        const float wk = cw[64 + k], bk = cb[64 + k];
        const int b = (64 + k) / 3 - 21;
        const float Gab = G[a * 32 + b];
        const float Sb  = G[22 * 32 + b];
        float lo = 0.125f * (wq * wk * Gab + wq * bk * Sa + bq * wk * Sb
                             + bq * bk * (float)NPOS);
        lg[c][k] = lo;
        mx = fmaxf(mx, lo);
    }
    float sum = 0.f;
    #pragma unroll
    for (int k = 0; k < 64; ++k) {
        float e = expf(lg[c][k] - mx);
        lg[c][k] = e; sum += e;
    }
    const float inv = 1.f / sum;
    float Ml[22];
    #pragma unroll
    for (int m = 0; m < 22; ++m) Ml[m] = 0.f;
    float bacc = 0.f;
    #pragma unroll
    for (int k = 0; k < 64; ++k) {
        const float attn = lg[c][k] * inv;
        const int mm = (128 + k) / 3 - 42;
        Ml[mm] = fmaf(attn, cw[128 + k], Ml[mm]);
        bacc   = fmaf(attn, cb[128 + k], bacc);
    }
    #pragma unroll
    for (int m = 0; m < 22; ++m) M[c * 22 + m] = Ml[m];
    betaO[c] = bacc;
}

// Output kernel: 2 positions/thread, f32x2 loads, f32x2 nontemporal stores.
// __launch_bounds__(256,2): xv[64] f32x2 needs 128 live VGPRs; default
// occupancy heuristic (~64 VGPR) serializes the loads.
__global__ __launch_bounds__(256, 2) void csa_k4(
    const float* __restrict__ x, const float* __restrict__ lng,
    const float* __restrict__ lnb, const float* __restrict__ M,
    const float* __restrict__ betaO, float* __restrict__ out)
{
    const int n0 = (blockIdx.x * 256 + threadIdx.x) * 2;
    f32x2 xv[64];
    f32x2 s = {0.f, 0.f}, sq = s;
    #pragma unroll
    for (int c = 0; c < 64; ++c) {
        f32x2 v = *(const f32x2*)(x + (size_t)c * NPOS + n0);
        xv[c] = v; s += v; sq += v * v;
    }
    const f32x2 mu = s * (1.f/64.f);
    const f32x2 var = sq * (1.f/64.f) - mu * mu;
    const float rin0 = rsqrtf(fmaxf(var[0], 0.f) + LN_EPS);
    const float rin1 = rsqrtf(fmaxf(var[1], 0.f) + LN_EPS);
    f32x2 y[22];
    #pragma unroll
    for (int m = 0; m < 22; ++m) {
        const float g = lng[42 + m], b = lnb[42 + m];
        y[m][0] = fmaf((xv[42 + m][0] - mu[0]) * rin0, g, b);
        y[m][1] = fmaf((xv[42 + m][1] - mu[1]) * rin1, g, b);
    }
    #pragma unroll
    for (int c = 0; c < 64; ++c) {
        const float bb = betaO[c];
        f32x2 a = {bb, bb};
        #pragma unroll
        for (int m = 0; m < 22; ++m) {
            const float w = M[c * 22 + m];       // uniform -> scalar
            a[0] = fmaf(w, y[m][0], a[0]);
            a[1] = fmaf(w, y[m][1], a[1]);
        }
        f32x2 o = xv[c] + a;
        __builtin_nontemporal_store(o, (f32x2*)(out + (size_t)c * NPOS + n0));
    }
}

extern "C" void kernel_launch(void* const* d_in, const int* in_sizes, int n_in,
                              void* d_out, int out_size, void* d_ws, size_t ws_size,
                              hipStream_t stream) {
    const float* x   = (const float*)d_in[0];
    const float* lng = (const float*)d_in[1];
    const float* lnb = (const float*)d_in[2];
    const float* cw  = (const float*)d_in[3];
    const float* cb  = (const float*)d_in[4];
    float* out = (float*)d_out;

    float* wsf = (float*)d_ws;
    float* Gf  = wsf;                     // 1024 floats
    float* Mf  = wsf + 1024;              // 64*22
    float* Bf  = wsf + 1024 + 64 * 22;    // 64
    float* Pf  = wsf + 4096;              // partials (576 * 1024 floats)

    hipLaunchKernelGGL(csa_k1, dim3(K1_BLOCKS), dim3(256), 0, stream,
                       x, lng, lnb, Pf);
    hipLaunchKernelGGL(csa_k2, dim3(4), dim3(256), 0, stream, Pf, Gf);
    hipLaunchKernelGGL(csa_k3, dim3(1), dim3(64), 0, stream, Gf, cw, cb, Mf, Bf);
    hipLaunchKernelGGL(csa_k4, dim3(NPOS / 512), dim3(256), 0, stream,
                       x, lng, lnb, Mf, Bf, out);
}

// Round 7
// 140.115 us; speedup vs baseline: 1.1967x; 1.0850x over previous
//
#include <hip/hip_runtime.h>

#define NPOS 589824   // 64*96*96
#define LN_EPS 1e-5f

typedef _Float16 half8 __attribute__((ext_vector_type(8)));
typedef _Float16 half2_t __attribute__((ext_vector_type(2)));
typedef float f32x4 __attribute__((ext_vector_type(4)));
typedef float f32x2 __attribute__((ext_vector_type(2)));

#define K1_BLOCKS 768
#define K1_CPB 3      // 3 chunks of 256 positions: 768*3*256 == NPOS
#define YSTR 264      // f16 row stride; 264*2/4 % 32 == 4 -> 2-way max (free)

// ws layout (floats): [0,1024) G ; [1024,2432) M 64x22 ; [2432,2496) beta
// [4096, 4096 + K1_BLOCKS*1024) partials = 3.146 MB (exactly round-1's proven fit)

// LN + Gram. One position per thread. PURE load batch into xv[64] (array =
// in-flight buffer, MLP~64, k4-proven pattern), THEN stats, THEN y->LDS.
// Y rows: 0..42 = y channels, 43 = ones, 44 = zeros.
// A rows r: r<22->r, r==22->43(ones), else 44.  B rows r (=ch 21+r):
// r<=22 -> 21+r (22->43 ones), else 44.
__global__ __launch_bounds__(256, 3) void csa_k1(
    const float* __restrict__ x, const float* __restrict__ lng,
    const float* __restrict__ lnb, float* __restrict__ partials)
{
    __shared__ __align__(16) _Float16 Y[45][YSTR];   // 23.8 KB
    const int tid = threadIdx.x;
    const int lane = tid & 63;
    const int wv = tid >> 6;

    for (int i = tid; i < YSTR; i += 256) {
        Y[43][i] = (_Float16)1.0f;
        Y[44][i] = (_Float16)0.0f;
    }

    f32x4 acc00 = {0.f,0.f,0.f,0.f}, acc01 = acc00, acc10 = acc00, acc11 = acc00;
    const int row = lane & 15;
    const int sub = (lane >> 4) & 3;
    const int kbase = wv * 64 + sub * 8;             // wave's 64-wide K slice
    const int r16 = row + 16;
    const int ra1 = (r16 < 22) ? r16 : ((r16 == 22) ? 43 : 44);
    const int rb1 = (r16 < 22) ? (r16 + 21) : ((r16 == 22) ? 43 : 44);
    const int pos0 = blockIdx.x * (K1_CPB * 256);

    for (int ck = 0; ck < K1_CPB; ++ck) {
        const int n = pos0 + ck * 256 + tid;
        float xv[64];
        #pragma unroll
        for (int c = 0; c < 64; ++c)                 // pure batch: no math,
            xv[c] = x[(size_t)c * NPOS + n];         // no cvt, no waits chained
        float s = 0.f, sq = 0.f;
        #pragma unroll
        for (int c = 0; c < 64; ++c) {
            s += xv[c]; sq = fmaf(xv[c], xv[c], sq);
        }
        const float mu  = s * (1.f/64.f);
        const float var = fmaf(-mu, mu, sq * (1.f/64.f));
        const float rin = rsqrtf(fmaxf(var, 0.f) + LN_EPS);
        #pragma unroll
        for (int c = 0; c < 43; ++c) {
            const float yv = fmaf((xv[c] - mu) * rin, lng[c], lnb[c]);
            Y[c][tid] = (_Float16)yv;
        }
        __syncthreads();
        #pragma unroll
        for (int s2 = 0; s2 < 2; ++s2) {
            const int kk = kbase + s2 * 32;
            half8 a0 = *(const half8*)&Y[row][kk];
            half8 a1 = *(const half8*)&Y[ra1][kk];
            half8 b0 = *(const half8*)&Y[row + 21][kk];
            half8 b1 = *(const half8*)&Y[rb1][kk];
            acc00 = __builtin_amdgcn_mfma_f32_16x16x32_f16(a0, b0, acc00, 0, 0, 0);
            acc01 = __builtin_amdgcn_mfma_f32_16x16x32_f16(a0, b1, acc01, 0, 0, 0);
            acc10 = __builtin_amdgcn_mfma_f32_16x16x32_f16(a1, b0, acc10, 0, 0, 0);
            acc11 = __builtin_amdgcn_mfma_f32_16x16x32_f16(a1, b1, acc11, 0, 0, 0);
        }
        __syncthreads();
    }
    // block-level reduce of the 4 waves' fragments (reuse Y as float scratch)
    float* G32 = (float*)&Y[0][0];
    for (int e = tid; e < 1024; e += 256) G32[e] = 0.f;
    __syncthreads();
    const int r0 = (lane >> 4) * 4, c0 = lane & 15;
    #pragma unroll
    for (int r = 0; r < 4; ++r) {
        atomicAdd(&G32[(r0 + r) * 32 + c0],            acc00[r]);
        atomicAdd(&G32[(r0 + r) * 32 + 16 + c0],       acc01[r]);
        atomicAdd(&G32[(16 + r0 + r) * 32 + c0],       acc10[r]);
        atomicAdd(&G32[(16 + r0 + r) * 32 + 16 + c0],  acc11[r]);
    }
    __syncthreads();
    for (int e = tid; e < 1024; e += 256)
        partials[blockIdx.x * 1024 + e] = G32[e];
}

__global__ __launch_bounds__(256) void csa_k2(const float* __restrict__ partials,
                                              float* __restrict__ gfin)
{
    const int e = blockIdx.x * 256 + threadIdx.x;  // 0..1023
    float s = 0.f;
    for (int b = 0; b < K1_BLOCKS; ++b) s += partials[b * 1024 + e];
    gfin[e] = s;
}

__global__ void csa_k3(const float* __restrict__ G, const float* __restrict__ cw,
                       const float* __restrict__ cb, float* __restrict__ M,
                       float* __restrict__ betaO)
{
    const int c = threadIdx.x;       // 64 threads, one output row each
    __shared__ float lg[64][65];
    const float wq = cw[c], bq = cb[c];
    const int a = c / 3;
    const float Sa = G[a * 32 + 22];
    float mx = -1e30f;
    #pragma unroll
    for (int k = 0; k < 64; ++k) {
        const float wk = cw[64 + k], bk = cb[64 + k];
        const int b = (64 + k) / 3 - 21;
        const float Gab = G[a * 32 + b];
        const float Sb  = G[22 * 32 + b];
        float lo = 0.125f * (wq * wk * Gab + wq * bk * Sa + bq * wk * Sb
                             + bq * bk * (float)NPOS);
        lg[c][k] = lo;
        mx = fmaxf(mx, lo);
    }
    float sum = 0.f;
    #pragma unroll
    for (int k = 0; k < 64; ++k) {
        float e = expf(lg[c][k] - mx);
        lg[c][k] = e; sum += e;
    }
    const float inv = 1.f / sum;
    float Ml[22];
    #pragma unroll
    for (int m = 0; m < 22; ++m) Ml[m] = 0.f;
    float bacc = 0.f;
    #pragma unroll
    for (int k = 0; k < 64; ++k) {
        const float attn = lg[c][k] * inv;
        const int mm = (128 + k) / 3 - 42;
        Ml[mm] = fmaf(attn, cw[128 + k], Ml[mm]);
        bacc   = fmaf(attn, cb[128 + k], bacc);
    }
    #pragma unroll
    for (int m = 0; m < 22; ++m) M[c * 22 + m] = Ml[m];
    betaO[c] = bacc;
}

// Output kernel: 2 positions/thread, f32x2 loads, f32x2 nontemporal stores.
// xv[64] f32x2 = 128 live VGPRs -> launch_bounds(256,2).
__global__ __launch_bounds__(256, 2) void csa_k4(
    const float* __restrict__ x, const float* __restrict__ lng,
    const float* __restrict__ lnb, const float* __restrict__ M,
    const float* __restrict__ betaO, float* __restrict__ out)
{
    const int n0 = (blockIdx.x * 256 + threadIdx.x) * 2;
    f32x2 xv[64];
    f32x2 s = {0.f, 0.f}, sq = s;
    #pragma unroll
    for (int c = 0; c < 64; ++c) {
        f32x2 v = *(const f32x2*)(x + (size_t)c * NPOS + n0);
        xv[c] = v; s += v; sq += v * v;
    }
    const f32x2 mu = s * (1.f/64.f);
    const f32x2 var = sq * (1.f/64.f) - mu * mu;
    const float rin0 = rsqrtf(fmaxf(var[0], 0.f) + LN_EPS);
    const float rin1 = rsqrtf(fmaxf(var[1], 0.f) + LN_EPS);
    f32x2 y[22];
    #pragma unroll
    for (int m = 0; m < 22; ++m) {
        const float g = lng[42 + m], b = lnb[42 + m];
        y[m][0] = fmaf((xv[42 + m][0] - mu[0]) * rin0, g, b);
        y[m][1] = fmaf((xv[42 + m][1] - mu[1]) * rin1, g, b);
    }
    #pragma unroll
    for (int c = 0; c < 64; ++c) {
        const float bb = betaO[c];
        f32x2 a = {bb, bb};
        #pragma unroll
        for (int m = 0; m < 22; ++m) {
            const float w = M[c * 22 + m];       // uniform -> scalar
            a[0] = fmaf(w, y[m][0], a[0]);
            a[1] = fmaf(w, y[m][1], a[1]);
        }
        f32x2 o = xv[c] + a;
        __builtin_nontemporal_store(o, (f32x2*)(out + (size_t)c * NPOS + n0));
    }
}

extern "C" void kernel_launch(void* const* d_in, const int* in_sizes, int n_in,
                              void* d_out, int out_size, void* d_ws, size_t ws_size,
                              hipStream_t stream) {
    const float* x   = (const float*)d_in[0];
    const float* lng = (const float*)d_in[1];
    const float* lnb = (const float*)d_in[2];
    const float* cw  = (const float*)d_in[3];
    const float* cb  = (const float*)d_in[4];
    float* out = (float*)d_out;

    float* wsf = (float*)d_ws;
    float* Gf  = wsf;                     // 1024 floats
    float* Mf  = wsf + 1024;              // 64*22
    float* Bf  = wsf + 1024 + 64 * 22;    // 64
    float* Pf  = wsf + 4096;              // partials (768 * 1024 floats)

    hipLaunchKernelGGL(csa_k1, dim3(K1_BLOCKS), dim3(256), 0, stream,
                       x, lng, lnb, Pf);
    hipLaunchKernelGGL(csa_k2, dim3(4), dim3(256), 0, stream, Pf, Gf);
    hipLaunchKernelGGL(csa_k3, dim3(1), dim3(64), 0, stream, Gf, cw, cb, Mf, Bf);
    hipLaunchKernelGGL(csa_k4, dim3(NPOS / 512), dim3(256), 0, stream,
                       x, lng, lnb, Mf, Bf, out);
}